// Round 10
// baseline (441.560 us; speedup 1.0000x reference)
//
#include <hip/hip_runtime.h>

#define NN 100000
#define NNP 100096            // padded row count (multiple of 128)
#define NE 1600000
#define NBK 391               // node buckets of 256 (dst >> 8)
#define SCCH 4096             // edges per scatter/hist block
#define NSC ((NE + SCCH - 1) / SCCH)   // 391

typedef __attribute__((ext_vector_type(8))) short bf16x8;
typedef __attribute__((ext_vector_type(4))) float f32x4;

__device__ __forceinline__ float bf2f(unsigned short u) {
    unsigned int v = ((unsigned int)u) << 16;
    return __builtin_bit_cast(float, v);
}
__device__ __forceinline__ unsigned short f2bf(float f) {
    unsigned int u = __builtin_bit_cast(unsigned int, f);
    u += 0x7FFFu + ((u >> 16) & 1u);          // RNE
    return (unsigned short)(u >> 16);
}
__device__ __forceinline__ unsigned int pk2(float lo, float hi) {
    return (unsigned int)f2bf(lo) | ((unsigned int)f2bf(hi) << 16);
}
__device__ __forceinline__ float bflo(unsigned int v) {
    return __builtin_bit_cast(float, v << 16);
}
__device__ __forceinline__ float bfhi(unsigned int v) {
    return __builtin_bit_cast(float, v & 0xFFFF0000u);
}

// ---------------- bucketed CSR build ----------------

__global__ __launch_bounds__(256) void kb_hist(const int* __restrict__ dst,
                                               int* __restrict__ bcnt) {
    __shared__ int lh[NBK];
    int tid = threadIdx.x;
    for (int i = tid; i < NBK; i += 256) lh[i] = 0;
    __syncthreads();
    int base = blockIdx.x * SCCH;
    int lim = min(SCCH, NE - base);
    for (int i = tid; i < lim; i += 256)
        atomicAdd(&lh[dst[base + i] >> 8], 1);
    __syncthreads();
    for (int i = tid; i < NBK; i += 256)
        if (lh[i]) atomicAdd(&bcnt[i], lh[i]);
}

__global__ __launch_bounds__(512) void kb_scan(const int* __restrict__ bcnt,
                                               int* __restrict__ boff,
                                               int* __restrict__ bcur) {
    __shared__ int s[512];
    int tid = threadIdx.x;
    int v = (tid < NBK) ? bcnt[tid] : 0;
    s[tid] = v;
    __syncthreads();
#pragma unroll
    for (int off = 1; off < 512; off <<= 1) {
        int t = (tid >= off) ? s[tid - off] : 0;
        __syncthreads();
        if (tid >= off) s[tid] += t;
        __syncthreads();
    }
    if (tid < NBK) {
        int e = s[tid] - v;       // exclusive
        boff[tid] = e;
        bcur[tid] = e;
    }
    if (tid == 0) boff[NBK] = NE;
}

__global__ __launch_bounds__(256) void kb_scatter(const int* __restrict__ src,
                                                  const int* __restrict__ dst,
                                                  int* __restrict__ bcur,
                                                  unsigned long long* __restrict__ ebuf) {
    __shared__ int lh[NBK], lbase[NBK];
    int tid = threadIdx.x;
    for (int i = tid; i < NBK; i += 256) lh[i] = 0;
    __syncthreads();
    int base = blockIdx.x * SCCH;
    int lim = min(SCCH, NE - base);
    for (int i = tid; i < lim; i += 256)
        atomicAdd(&lh[dst[base + i] >> 8], 1);
    __syncthreads();
    for (int i = tid; i < NBK; i += 256)
        lbase[i] = lh[i] ? atomicAdd(&bcur[i], lh[i]) : 0;
    __syncthreads();
    for (int i = tid; i < NBK; i += 256) lh[i] = 0;
    __syncthreads();
    for (int i = tid; i < lim; i += 256) {
        int d = dst[base + i];
        int s = src[base + i];
        int b = d >> 8;
        int off = atomicAdd(&lh[b], 1);
        ebuf[(size_t)lbase[b] + off] =
            ((unsigned long long)(unsigned)d << 32) | (unsigned)s;
    }
}

__global__ __launch_bounds__(256) void kb_csr(const unsigned long long* __restrict__ ebuf,
                                              const int* __restrict__ boff,
                                              int* __restrict__ row_off,
                                              int* __restrict__ csr) {
    __shared__ int sdeg[256], spre[256];
    int bkt = blockIdx.x;
    int tid = threadIdx.x;
    int nbase = bkt << 8;
    int ebeg = boff[bkt], eend = boff[bkt + 1];
    sdeg[tid] = 0;
    __syncthreads();
    for (int e = ebeg + tid; e < eend; e += 256) {
        int d = (int)(ebuf[e] >> 32);
        atomicAdd(&sdeg[d & 255], 1);
    }
    __syncthreads();
    spre[tid] = sdeg[tid];
    __syncthreads();
#pragma unroll
    for (int off = 1; off < 256; off <<= 1) {
        int t = (tid >= off) ? spre[tid - off] : 0;
        __syncthreads();
        if (tid >= off) spre[tid] += t;
        __syncthreads();
    }
    int excl = spre[tid] - sdeg[tid];
    if (nbase + tid < NN) row_off[nbase + tid] = ebeg + excl;
    if (bkt == 0 && tid == 0) row_off[NN] = NE;
    __syncthreads();
    sdeg[tid] = excl;                 // reuse as cursor
    __syncthreads();
    for (int e = ebeg + tid; e < eend; e += 256) {
        unsigned long long pv = ebuf[e];
        int d = (int)(pv >> 32);
        int s = (int)(unsigned)pv;
        int p = atomicAdd(&sdeg[d & 255], 1);
        csr[ebeg + p] = s;
    }
}

// ---------------- prep: W -> WT bf16 ----------------

__global__ __launch_bounds__(256) void k_prep_wt(const float* __restrict__ Wl_stack,
                                                 const float* __restrict__ Wr_stack,
                                                 const float* __restrict__ Wl_out,
                                                 const float* __restrict__ Wr_out,
                                                 unsigned short* __restrict__ WT) {
    int i = blockIdx.x * 256 + threadIdx.x;
    const int L3OFF = 3 * 256 * 128;     // 98304
    const int TOT = L3OFF + 128 * 128;   // 114688
    if (i >= TOT) return;
    float v;
    if (i < L3OFF) {
        int l = i / (256 * 128);
        int r = i % (256 * 128);
        int c = r / 128;                 // output col within [Wl|Wr]
        int k = r % 128;
        v = (c < 128) ? Wl_stack[(size_t)(l * 128 + k) * 128 + c]
                      : Wr_stack[(size_t)(l * 128 + k) * 128 + (c - 128)];
    } else {
        int r = i - L3OFF;
        int c = r / 128;
        int k = r % 128;
        v = (c < 64) ? Wl_out[(size_t)k * 64 + c]
                     : Wr_out[(size_t)k * 64 + (c - 64)];
    }
    WT[i] = f2bf(v);
}

// ---------------- MFMA dual GEMM: Y|Z = A @ [Wl|Wr] ----------------

template <int NOUT, bool F32IN>
__global__ __launch_bounds__(256) void k_mm(const void* __restrict__ Ain,
                                            const unsigned short* __restrict__ WT,
                                            unsigned short* __restrict__ Y,
                                            unsigned short* __restrict__ Z) {
    constexpr int HALVES = NOUT / 64;   // 2 for 128, 1 for 64
    int tid = threadIdx.x;
    int wave = tid >> 6, l = tid & 63;
    int lrow = l & 15, g = l >> 4;
    int rbase = blockIdx.x * 128 + wave * 32;

    bf16x8 af[2][4];
#pragma unroll
    for (int s = 0; s < 2; ++s) {
        int row = rbase + s * 16 + lrow;
#pragma unroll
        for (int ks = 0; ks < 4; ++ks) {
            if (F32IN) {
                int rc = row < NN ? row : NN - 1;   // x is not padded past NN
                const float* ap = (const float*)Ain + (size_t)rc * 128 + ks * 32 + g * 8;
                float4 a = *(const float4*)ap;
                float4 b = *(const float4*)(ap + 4);
                uint4 u;
                u.x = pk2(a.x, a.y); u.y = pk2(a.z, a.w);
                u.z = pk2(b.x, b.y); u.w = pk2(b.z, b.w);
                af[s][ks] = __builtin_bit_cast(bf16x8, u);
            } else {
                af[s][ks] = *(const bf16x8*)((const unsigned short*)Ain
                                             + (size_t)row * 128 + ks * 32 + g * 8);
            }
        }
    }

#pragma unroll
    for (int h = 0; h < HALVES; ++h) {
#pragma unroll
        for (int cg8 = 0; cg8 < 8; ++cg8) {
            int c = (h * 8 + cg8) * 16 + lrow;
            bf16x8 bfr[4];
#pragma unroll
            for (int ks = 0; ks < 4; ++ks)
                bfr[ks] = *(const bf16x8*)(WT + (size_t)c * 128 + ks * 32 + g * 8);
            unsigned short* dstp = (c < NOUT) ? Y : Z;
            int col = (c < NOUT) ? c : c - NOUT;
#pragma unroll
            for (int s = 0; s < 2; ++s) {
                f32x4 acc = {0.f, 0.f, 0.f, 0.f};
#pragma unroll
                for (int ks = 0; ks < 4; ++ks)
                    acc = __builtin_amdgcn_mfma_f32_16x16x32_bf16(af[s][ks], bfr[ks], acc, 0, 0, 0);
                int r0 = rbase + s * 16 + g * 4;
#pragma unroll
                for (int r = 0; r < 4; ++r)
                    dstp[(size_t)(r0 + r) * NOUT + col] = f2bf(acc[r]);
            }
        }
    }
}

// ---------------- aggregation: multi-edge-per-wave gather ----------------
// NOUT=128: 2 edges/wave-load (32 lanes x uint2 = 256B row), 16 rows in flight.
// NOUT=64 : 4 edges/wave-load (16 lanes x uint2 = 128B row).

template <int NOUT, bool RELU>
__global__ __launch_bounds__(256) void k_aggb(const unsigned short* __restrict__ Y,
                                              const unsigned short* __restrict__ Z,
                                              const int* __restrict__ row_off,
                                              const int* __restrict__ csr,
                                              const float* __restrict__ b,
                                              unsigned short* __restrict__ outb,
                                              float* __restrict__ outf) {
    int lane = threadIdx.x & 63;
    int n = __builtin_amdgcn_readfirstlane(blockIdx.x * 4 + (threadIdx.x >> 6));
    if (n >= NN) return;
    int beg = __builtin_amdgcn_readfirstlane(row_off[n]);
    int end = __builtin_amdgcn_readfirstlane(row_off[n + 1]);
    float inv = (end > beg) ? 1.0f / (float)(end - beg) : 0.0f;

    if (NOUT == 128) {
        int half = lane >> 5;             // 0/1: which edge of a pair
        int li = lane & 31;               // 8B chunk within row
        const unsigned short* Yr = Y + li * 4;
        float a0 = 0.f, a1 = 0.f, a2 = 0.f, a3 = 0.f;
        int e = beg;
        for (; e + 16 <= end; e += 16) {
            int s0 = csr[e + 0], s1 = csr[e + 1], s2 = csr[e + 2], s3 = csr[e + 3];
            int s4 = csr[e + 4], s5 = csr[e + 5], s6 = csr[e + 6], s7 = csr[e + 7];
            int s8 = csr[e + 8], s9 = csr[e + 9], sa = csr[e + 10], sb = csr[e + 11];
            int sc = csr[e + 12], sd = csr[e + 13], se = csr[e + 14], sf = csr[e + 15];
            uint2 v0 = *(const uint2*)(Yr + (size_t)(half ? s1 : s0) * 128);
            uint2 v1 = *(const uint2*)(Yr + (size_t)(half ? s3 : s2) * 128);
            uint2 v2 = *(const uint2*)(Yr + (size_t)(half ? s5 : s4) * 128);
            uint2 v3 = *(const uint2*)(Yr + (size_t)(half ? s7 : s6) * 128);
            uint2 v4 = *(const uint2*)(Yr + (size_t)(half ? s9 : s8) * 128);
            uint2 v5 = *(const uint2*)(Yr + (size_t)(half ? sb : sa) * 128);
            uint2 v6 = *(const uint2*)(Yr + (size_t)(half ? sd : sc) * 128);
            uint2 v7 = *(const uint2*)(Yr + (size_t)(half ? sf : se) * 128);
            a0 += bflo(v0.x) + bflo(v1.x) + bflo(v2.x) + bflo(v3.x)
                + bflo(v4.x) + bflo(v5.x) + bflo(v6.x) + bflo(v7.x);
            a1 += bfhi(v0.x) + bfhi(v1.x) + bfhi(v2.x) + bfhi(v3.x)
                + bfhi(v4.x) + bfhi(v5.x) + bfhi(v6.x) + bfhi(v7.x);
            a2 += bflo(v0.y) + bflo(v1.y) + bflo(v2.y) + bflo(v3.y)
                + bflo(v4.y) + bflo(v5.y) + bflo(v6.y) + bflo(v7.y);
            a3 += bfhi(v0.y) + bfhi(v1.y) + bfhi(v2.y) + bfhi(v3.y)
                + bfhi(v4.y) + bfhi(v5.y) + bfhi(v6.y) + bfhi(v7.y);
        }
        for (; e + 4 <= end; e += 4) {
            int s0 = csr[e + 0], s1 = csr[e + 1], s2 = csr[e + 2], s3 = csr[e + 3];
            uint2 v0 = *(const uint2*)(Yr + (size_t)(half ? s1 : s0) * 128);
            uint2 v1 = *(const uint2*)(Yr + (size_t)(half ? s3 : s2) * 128);
            a0 += bflo(v0.x) + bflo(v1.x);
            a1 += bfhi(v0.x) + bfhi(v1.x);
            a2 += bflo(v0.y) + bflo(v1.y);
            a3 += bfhi(v0.y) + bfhi(v1.y);
        }
        for (; e + 2 <= end; e += 2) {
            int s0 = csr[e + 0], s1 = csr[e + 1];
            uint2 v0 = *(const uint2*)(Yr + (size_t)(half ? s1 : s0) * 128);
            a0 += bflo(v0.x);
            a1 += bfhi(v0.x);
            a2 += bflo(v0.y);
            a3 += bfhi(v0.y);
        }
        if (e < end) {                     // single leftover: half 0 only
            int s0 = csr[e];
            uint2 v0 = *(const uint2*)(Yr + (size_t)s0 * 128);
            if (!half) {
                a0 += bflo(v0.x);
                a1 += bfhi(v0.x);
                a2 += bflo(v0.y);
                a3 += bfhi(v0.y);
            }
        }
        // combine halves
        a0 += __shfl_xor(a0, 32);
        a1 += __shfl_xor(a1, 32);
        a2 += __shfl_xor(a2, 32);
        a3 += __shfl_xor(a3, 32);
        if (half == 0) {
            uint2 zv = *(const uint2*)(Z + (size_t)n * 128 + li * 4);
            float4 bb = *(const float4*)(b + li * 4);
            float o0 = a0 * inv + bflo(zv.x) + bb.x;
            float o1 = a1 * inv + bfhi(zv.x) + bb.y;
            float o2 = a2 * inv + bflo(zv.y) + bb.z;
            float o3 = a3 * inv + bfhi(zv.y) + bb.w;
            if (RELU) {
                o0 = o0 > 0.f ? o0 : 0.1f * o0;
                o1 = o1 > 0.f ? o1 : 0.1f * o1;
                o2 = o2 > 0.f ? o2 : 0.1f * o2;
                o3 = o3 > 0.f ? o3 : 0.1f * o3;
            }
            uint2 w;
            w.x = pk2(o0, o1);
            w.y = pk2(o2, o3);
            *(uint2*)(outb + (size_t)n * 128 + li * 4) = w;
        }
    } else {
        int q = lane >> 4;                // 0..3: which edge of a quad
        int li = lane & 15;
        const unsigned short* Yr = Y + li * 4;
        float a0 = 0.f, a1 = 0.f, a2 = 0.f, a3 = 0.f;
        int e = beg;
        for (; e + 16 <= end; e += 16) {
#pragma unroll
            for (int g = 0; g < 4; ++g) {
                int t0 = csr[e + g * 4 + 0], t1 = csr[e + g * 4 + 1];
                int t2 = csr[e + g * 4 + 2], t3 = csr[e + g * 4 + 3];
                int b0 = (q & 2) ? t2 : t0;
                int b1 = (q & 2) ? t3 : t1;
                int sel = (q & 1) ? b1 : b0;
                uint2 v = *(const uint2*)(Yr + (size_t)sel * 64);
                a0 += bflo(v.x);
                a1 += bfhi(v.x);
                a2 += bflo(v.y);
                a3 += bfhi(v.y);
            }
        }
        for (; e + 4 <= end; e += 4) {
            int t0 = csr[e + 0], t1 = csr[e + 1], t2 = csr[e + 2], t3 = csr[e + 3];
            int b0 = (q & 2) ? t2 : t0;
            int b1 = (q & 2) ? t3 : t1;
            int sel = (q & 1) ? b1 : b0;
            uint2 v = *(const uint2*)(Yr + (size_t)sel * 64);
            a0 += bflo(v.x);
            a1 += bfhi(v.x);
            a2 += bflo(v.y);
            a3 += bfhi(v.y);
        }
        for (; e < end; ++e) {             // singles: quad 0 only
            int s0 = csr[e];
            uint2 v = *(const uint2*)(Yr + (size_t)s0 * 64);
            if (q == 0) {
                a0 += bflo(v.x);
                a1 += bfhi(v.x);
                a2 += bflo(v.y);
                a3 += bfhi(v.y);
            }
        }
        a0 += __shfl_xor(a0, 16);
        a1 += __shfl_xor(a1, 16);
        a2 += __shfl_xor(a2, 16);
        a3 += __shfl_xor(a3, 16);
        a0 += __shfl_xor(a0, 32);
        a1 += __shfl_xor(a1, 32);
        a2 += __shfl_xor(a2, 32);
        a3 += __shfl_xor(a3, 32);
        if (q == 0) {
            uint2 zv = *(const uint2*)(Z + (size_t)n * 64 + li * 4);
            float4 bb = *(const float4*)(b + li * 4);
            float4 o;
            o.x = a0 * inv + bflo(zv.x) + bb.x;
            o.y = a1 * inv + bfhi(zv.x) + bb.y;
            o.z = a2 * inv + bflo(zv.y) + bb.z;
            o.w = a3 * inv + bfhi(zv.y) + bb.w;
            if (RELU) {
                o.x = o.x > 0.f ? o.x : 0.1f * o.x;
                o.y = o.y > 0.f ? o.y : 0.1f * o.y;
                o.z = o.z > 0.f ? o.z : 0.1f * o.z;
                o.w = o.w > 0.f ? o.w : 0.1f * o.w;
            }
            *(float4*)(outf + (size_t)n * 64 + li * 4) = o;
        }
    }
}

// ---------------- launch ----------------

extern "C" void kernel_launch(void* const* d_in, const int* in_sizes, int n_in,
                              void* d_out, int out_size, void* d_ws, size_t ws_size,
                              hipStream_t stream) {
    const float* x        = (const float*)d_in[0];
    const int*   ei       = (const int*)d_in[1];
    const float* Wl_stack = (const float*)d_in[2];
    const float* Wr_stack = (const float*)d_in[3];
    const float* b_stack  = (const float*)d_in[4];
    const float* Wl_out   = (const float*)d_in[5];
    const float* Wr_out   = (const float*)d_in[6];
    const float* b_out    = (const float*)d_in[7];
    float* out = (float*)d_out;

    unsigned short* hb = (unsigned short*)d_ws;        // [NNP,128]
    unsigned short* Yb = hb + (size_t)NNP * 128;       // [NNP,128]
    unsigned short* Zb = Yb + (size_t)NNP * 128;       // [NNP,128]
    unsigned short* WT = Zb + (size_t)NNP * 128;       // 114688 elems
    unsigned long long* ebuf = (unsigned long long*)(WT + 114688);  // [NE]
    int* row_off = (int*)(ebuf + NE);                  // [NN+1]
    int* csr     = row_off + NN + 1;                   // [NE]
    int* bcnt    = csr + NE;                           // [NBK]
    int* boff    = bcnt + NBK;                         // [NBK+1]
    int* bcur    = boff + NBK + 1;                     // [NBK]

    const int* src = ei;
    const int* dst = ei + NE;

    // bucketed CSR build
    (void)hipMemsetAsync(bcnt, 0, NBK * sizeof(int), stream);
    kb_hist<<<NSC, 256, 0, stream>>>(dst, bcnt);
    kb_scan<<<1, 512, 0, stream>>>(bcnt, boff, bcur);
    kb_scatter<<<NSC, 256, 0, stream>>>(src, dst, bcur, ebuf);
    kb_csr<<<NBK, 256, 0, stream>>>(ebuf, boff, row_off, csr);

    // weights -> bf16 transposed
    k_prep_wt<<<448, 256, 0, stream>>>(Wl_stack, Wr_stack, Wl_out, Wr_out, WT);

    // layer 0 (fp32 x read directly, converted in-register)
    k_mm<128, true><<<NNP / 128, 256, 0, stream>>>(x, WT, Yb, Zb);
    k_aggb<128, true><<<(NN + 3) / 4, 256, 0, stream>>>(Yb, Zb, row_off, csr,
                                                        b_stack, hb, nullptr);
    // layers 1..2
    for (int l = 1; l < 3; ++l) {
        k_mm<128, false><<<NNP / 128, 256, 0, stream>>>(hb, WT + l * 32768, Yb, Zb);
        k_aggb<128, true><<<(NN + 3) / 4, 256, 0, stream>>>(Yb, Zb, row_off, csr,
                                                            b_stack + l * 128, hb, nullptr);
    }
    // final layer
    k_mm<64, false><<<NNP / 128, 256, 0, stream>>>(hb, WT + 98304, Yb, Zb);
    k_aggb<64, false><<<(NN + 3) / 4, 256, 0, stream>>>(Yb, Zb, row_off, csr,
                                                        b_out, nullptr, out);
}

// Round 11
// 414.188 us; speedup vs baseline: 1.0661x; 1.0661x over previous
//
#include <hip/hip_runtime.h>

#define NN 100000
#define NNP 100096            // padded row count (multiple of 128)
#define NE 1600000
#define NBK 391               // node buckets of 256 (dst >> 8)
#define SCCH 4096             // edges per scatter/hist block
#define NSC ((NE + SCCH - 1) / SCCH)   // 391

typedef __attribute__((ext_vector_type(8))) short bf16x8;
typedef __attribute__((ext_vector_type(4))) float f32x4;

__device__ __forceinline__ float bf2f(unsigned short u) {
    unsigned int v = ((unsigned int)u) << 16;
    return __builtin_bit_cast(float, v);
}
__device__ __forceinline__ unsigned short f2bf(float f) {
    unsigned int u = __builtin_bit_cast(unsigned int, f);
    u += 0x7FFFu + ((u >> 16) & 1u);          // RNE
    return (unsigned short)(u >> 16);
}
__device__ __forceinline__ unsigned int pk2(float lo, float hi) {
    return (unsigned int)f2bf(lo) | ((unsigned int)f2bf(hi) << 16);
}
__device__ __forceinline__ float bflo(unsigned int v) {
    return __builtin_bit_cast(float, v << 16);
}
__device__ __forceinline__ float bfhi(unsigned int v) {
    return __builtin_bit_cast(float, v & 0xFFFF0000u);
}

// ---------------- bucketed CSR build ----------------

__global__ __launch_bounds__(256) void kb_hist(const int* __restrict__ dst,
                                               int* __restrict__ bcnt) {
    __shared__ int lh[NBK];
    int tid = threadIdx.x;
    for (int i = tid; i < NBK; i += 256) lh[i] = 0;
    __syncthreads();
    int base = blockIdx.x * SCCH;
    int lim = min(SCCH, NE - base);
    for (int i = tid; i < lim; i += 256)
        atomicAdd(&lh[dst[base + i] >> 8], 1);
    __syncthreads();
    for (int i = tid; i < NBK; i += 256)
        if (lh[i]) atomicAdd(&bcnt[i], lh[i]);
}

__global__ __launch_bounds__(512) void kb_scan(const int* __restrict__ bcnt,
                                               int* __restrict__ boff,
                                               int* __restrict__ bcur) {
    __shared__ int s[512];
    int tid = threadIdx.x;
    int v = (tid < NBK) ? bcnt[tid] : 0;
    s[tid] = v;
    __syncthreads();
#pragma unroll
    for (int off = 1; off < 512; off <<= 1) {
        int t = (tid >= off) ? s[tid - off] : 0;
        __syncthreads();
        if (tid >= off) s[tid] += t;
        __syncthreads();
    }
    if (tid < NBK) {
        int e = s[tid] - v;       // exclusive
        boff[tid] = e;
        bcur[tid] = e;
    }
    if (tid == 0) boff[NBK] = NE;
}

__global__ __launch_bounds__(256) void kb_scatter(const int* __restrict__ src,
                                                  const int* __restrict__ dst,
                                                  int* __restrict__ bcur,
                                                  unsigned long long* __restrict__ ebuf) {
    __shared__ int lh[NBK], lbase[NBK];
    int tid = threadIdx.x;
    for (int i = tid; i < NBK; i += 256) lh[i] = 0;
    __syncthreads();
    int base = blockIdx.x * SCCH;
    int lim = min(SCCH, NE - base);
    for (int i = tid; i < lim; i += 256)
        atomicAdd(&lh[dst[base + i] >> 8], 1);
    __syncthreads();
    for (int i = tid; i < NBK; i += 256)
        lbase[i] = lh[i] ? atomicAdd(&bcur[i], lh[i]) : 0;
    __syncthreads();
    for (int i = tid; i < NBK; i += 256) lh[i] = 0;
    __syncthreads();
    for (int i = tid; i < lim; i += 256) {
        int d = dst[base + i];
        int s = src[base + i];
        int b = d >> 8;
        int off = atomicAdd(&lh[b], 1);
        ebuf[(size_t)lbase[b] + off] =
            ((unsigned long long)(unsigned)d << 32) | (unsigned)s;
    }
}

__global__ __launch_bounds__(256) void kb_csr(const unsigned long long* __restrict__ ebuf,
                                              const int* __restrict__ boff,
                                              int* __restrict__ row_off,
                                              int* __restrict__ csr) {
    __shared__ int sdeg[256], spre[256];
    int bkt = blockIdx.x;
    int tid = threadIdx.x;
    int nbase = bkt << 8;
    int ebeg = boff[bkt], eend = boff[bkt + 1];
    sdeg[tid] = 0;
    __syncthreads();
    for (int e = ebeg + tid; e < eend; e += 256) {
        int d = (int)(ebuf[e] >> 32);
        atomicAdd(&sdeg[d & 255], 1);
    }
    __syncthreads();
    spre[tid] = sdeg[tid];
    __syncthreads();
#pragma unroll
    for (int off = 1; off < 256; off <<= 1) {
        int t = (tid >= off) ? spre[tid - off] : 0;
        __syncthreads();
        if (tid >= off) spre[tid] += t;
        __syncthreads();
    }
    int excl = spre[tid] - sdeg[tid];
    if (nbase + tid < NN) row_off[nbase + tid] = ebeg + excl;
    if (bkt == 0 && tid == 0) row_off[NN] = NE;
    __syncthreads();
    sdeg[tid] = excl;                 // reuse as cursor
    __syncthreads();
    for (int e = ebeg + tid; e < eend; e += 256) {
        unsigned long long pv = ebuf[e];
        int d = (int)(pv >> 32);
        int s = (int)(unsigned)pv;
        int p = atomicAdd(&sdeg[d & 255], 1);
        csr[ebeg + p] = s;
    }
}

// ---------------- prep: W -> WT bf16 ----------------

__global__ __launch_bounds__(256) void k_prep_wt(const float* __restrict__ Wl_stack,
                                                 const float* __restrict__ Wr_stack,
                                                 const float* __restrict__ Wl_out,
                                                 const float* __restrict__ Wr_out,
                                                 unsigned short* __restrict__ WT) {
    int i = blockIdx.x * 256 + threadIdx.x;
    const int L3OFF = 3 * 256 * 128;     // 98304
    const int TOT = L3OFF + 128 * 128;   // 114688
    if (i >= TOT) return;
    float v;
    if (i < L3OFF) {
        int l = i / (256 * 128);
        int r = i % (256 * 128);
        int c = r / 128;                 // output col within [Wl|Wr]
        int k = r % 128;
        v = (c < 128) ? Wl_stack[(size_t)(l * 128 + k) * 128 + c]
                      : Wr_stack[(size_t)(l * 128 + k) * 128 + (c - 128)];
    } else {
        int r = i - L3OFF;
        int c = r / 128;
        int k = r % 128;
        v = (c < 64) ? Wl_out[(size_t)k * 64 + c]
                     : Wr_out[(size_t)k * 64 + (c - 64)];
    }
    WT[i] = f2bf(v);
}

// ---------------- MFMA dual GEMM: Y|Z = A @ [Wl|Wr] ----------------
// Retiled: for NOUT=128, each wave covers 64 rows x 128 cols (2x2 wave grid)
// -> per-wave WT reads halved vs 32x256. For NOUT=64: wave = 32 rows x 128 cols.

template <int NOUT, bool F32IN>
__global__ __launch_bounds__(256) void k_mm(const void* __restrict__ Ain,
                                            const unsigned short* __restrict__ WT,
                                            unsigned short* __restrict__ Y,
                                            unsigned short* __restrict__ Z) {
    constexpr int S = (NOUT == 128) ? 4 : 2;       // 16-row strips per wave
    int tid = threadIdx.x;
    int wave = tid >> 6, l = tid & 63;
    int lrow = l & 15, g = l >> 4;
    int rbase, cbase;
    if (NOUT == 128) {
        rbase = blockIdx.x * 128 + (wave & 1) * 64;
        cbase = (wave >> 1) * 128;
    } else {
        rbase = blockIdx.x * 128 + wave * 32;
        cbase = 0;
    }

    bf16x8 af[S][4];
#pragma unroll
    for (int s = 0; s < S; ++s) {
        int row = rbase + s * 16 + lrow;
#pragma unroll
        for (int ks = 0; ks < 4; ++ks) {
            if (F32IN) {
                int rc = row < NN ? row : NN - 1;   // x is not padded past NN
                const float* ap = (const float*)Ain + (size_t)rc * 128 + ks * 32 + g * 8;
                float4 a = *(const float4*)ap;
                float4 b = *(const float4*)(ap + 4);
                uint4 u;
                u.x = pk2(a.x, a.y); u.y = pk2(a.z, a.w);
                u.z = pk2(b.x, b.y); u.w = pk2(b.z, b.w);
                af[s][ks] = __builtin_bit_cast(bf16x8, u);
            } else {
                af[s][ks] = *(const bf16x8*)((const unsigned short*)Ain
                                             + (size_t)row * 128 + ks * 32 + g * 8);
            }
        }
    }

#pragma unroll
    for (int cg = 0; cg < 8; ++cg) {
        int c = cbase + cg * 16 + lrow;
        bf16x8 bfr[4];
#pragma unroll
        for (int ks = 0; ks < 4; ++ks)
            bfr[ks] = *(const bf16x8*)(WT + (size_t)c * 128 + ks * 32 + g * 8);
        unsigned short* dstp = (c < NOUT) ? Y : Z;
        int col = (c < NOUT) ? c : c - NOUT;
#pragma unroll
        for (int s = 0; s < S; ++s) {
            f32x4 acc = {0.f, 0.f, 0.f, 0.f};
#pragma unroll
            for (int ks = 0; ks < 4; ++ks)
                acc = __builtin_amdgcn_mfma_f32_16x16x32_bf16(af[s][ks], bfr[ks], acc, 0, 0, 0);
            int r0 = rbase + s * 16 + g * 4;
#pragma unroll
            for (int r = 0; r < 4; ++r)
                dstp[(size_t)(r0 + r) * NOUT + col] = f2bf(acc[r]);
        }
    }
}

// ---------------- aggregation (R9 form: bf16 gather, scalar edge stream) ----------------

template <int NOUT, bool RELU>
__global__ __launch_bounds__(256) void k_aggb(const unsigned short* __restrict__ Y,
                                              const unsigned short* __restrict__ Z,
                                              const int* __restrict__ row_off,
                                              const int* __restrict__ csr,
                                              const float* __restrict__ b,
                                              unsigned short* __restrict__ outb,
                                              float* __restrict__ outf) {
    int lane = threadIdx.x & 63;
    int n = __builtin_amdgcn_readfirstlane(blockIdx.x * 4 + (threadIdx.x >> 6));
    if (n >= NN) return;
    int beg = __builtin_amdgcn_readfirstlane(row_off[n]);
    int end = __builtin_amdgcn_readfirstlane(row_off[n + 1]);
    float inv = (end > beg) ? 1.0f / (float)(end - beg) : 0.0f;

    if (NOUT == 128) {
        const int lane2 = lane * 2;
        float a0 = 0.f, a1 = 0.f;
        int e = beg;
        for (; e + 8 <= end; e += 8) {
            int s0 = csr[e + 0], s1 = csr[e + 1], s2 = csr[e + 2], s3 = csr[e + 3];
            int s4 = csr[e + 4], s5 = csr[e + 5], s6 = csr[e + 6], s7 = csr[e + 7];
            unsigned int v0 = *(const unsigned int*)(Y + (size_t)s0 * 128 + lane2);
            unsigned int v1 = *(const unsigned int*)(Y + (size_t)s1 * 128 + lane2);
            unsigned int v2 = *(const unsigned int*)(Y + (size_t)s2 * 128 + lane2);
            unsigned int v3 = *(const unsigned int*)(Y + (size_t)s3 * 128 + lane2);
            unsigned int v4 = *(const unsigned int*)(Y + (size_t)s4 * 128 + lane2);
            unsigned int v5 = *(const unsigned int*)(Y + (size_t)s5 * 128 + lane2);
            unsigned int v6 = *(const unsigned int*)(Y + (size_t)s6 * 128 + lane2);
            unsigned int v7 = *(const unsigned int*)(Y + (size_t)s7 * 128 + lane2);
            a0 += bflo(v0) + bflo(v1) + bflo(v2) + bflo(v3)
                + bflo(v4) + bflo(v5) + bflo(v6) + bflo(v7);
            a1 += bfhi(v0) + bfhi(v1) + bfhi(v2) + bfhi(v3)
                + bfhi(v4) + bfhi(v5) + bfhi(v6) + bfhi(v7);
        }
        for (; e + 4 <= end; e += 4) {
            int s0 = csr[e + 0], s1 = csr[e + 1], s2 = csr[e + 2], s3 = csr[e + 3];
            unsigned int v0 = *(const unsigned int*)(Y + (size_t)s0 * 128 + lane2);
            unsigned int v1 = *(const unsigned int*)(Y + (size_t)s1 * 128 + lane2);
            unsigned int v2 = *(const unsigned int*)(Y + (size_t)s2 * 128 + lane2);
            unsigned int v3 = *(const unsigned int*)(Y + (size_t)s3 * 128 + lane2);
            a0 += bflo(v0) + bflo(v1) + bflo(v2) + bflo(v3);
            a1 += bfhi(v0) + bfhi(v1) + bfhi(v2) + bfhi(v3);
        }
        for (; e < end; ++e) {
            int s = csr[e];
            unsigned int v = *(const unsigned int*)(Y + (size_t)s * 128 + lane2);
            a0 += bflo(v);
            a1 += bfhi(v);
        }
        unsigned int zv = *(const unsigned int*)(Z + (size_t)n * 128 + lane2);
        float2 bb = *(const float2*)(b + lane2);
        float o0 = a0 * inv + bflo(zv) + bb.x;
        float o1 = a1 * inv + bfhi(zv) + bb.y;
        if (RELU) {
            o0 = o0 > 0.f ? o0 : 0.1f * o0;
            o1 = o1 > 0.f ? o1 : 0.1f * o1;
        }
        *(unsigned int*)(outb + (size_t)n * 128 + lane2) = pk2(o0, o1);
    } else {
        float a0 = 0.f;
        int e = beg;
        for (; e + 8 <= end; e += 8) {
            int s0 = csr[e + 0], s1 = csr[e + 1], s2 = csr[e + 2], s3 = csr[e + 3];
            int s4 = csr[e + 4], s5 = csr[e + 5], s6 = csr[e + 6], s7 = csr[e + 7];
            float f0 = bf2f(Y[(size_t)s0 * 64 + lane]);
            float f1 = bf2f(Y[(size_t)s1 * 64 + lane]);
            float f2 = bf2f(Y[(size_t)s2 * 64 + lane]);
            float f3 = bf2f(Y[(size_t)s3 * 64 + lane]);
            float f4 = bf2f(Y[(size_t)s4 * 64 + lane]);
            float f5 = bf2f(Y[(size_t)s5 * 64 + lane]);
            float f6 = bf2f(Y[(size_t)s6 * 64 + lane]);
            float f7 = bf2f(Y[(size_t)s7 * 64 + lane]);
            a0 += f0 + f1 + f2 + f3 + f4 + f5 + f6 + f7;
        }
        for (; e + 4 <= end; e += 4) {
            int s0 = csr[e + 0], s1 = csr[e + 1], s2 = csr[e + 2], s3 = csr[e + 3];
            float f0 = bf2f(Y[(size_t)s0 * 64 + lane]);
            float f1 = bf2f(Y[(size_t)s1 * 64 + lane]);
            float f2 = bf2f(Y[(size_t)s2 * 64 + lane]);
            float f3 = bf2f(Y[(size_t)s3 * 64 + lane]);
            a0 += f0 + f1 + f2 + f3;
        }
        for (; e < end; ++e) {
            int s = csr[e];
            a0 += bf2f(Y[(size_t)s * 64 + lane]);
        }
        float o = a0 * inv + bf2f(Z[(size_t)n * 64 + lane]) + b[lane];
        if (RELU) o = o > 0.f ? o : 0.1f * o;
        outf[(size_t)n * 64 + lane] = o;
    }
}

// ---------------- launch ----------------

extern "C" void kernel_launch(void* const* d_in, const int* in_sizes, int n_in,
                              void* d_out, int out_size, void* d_ws, size_t ws_size,
                              hipStream_t stream) {
    const float* x        = (const float*)d_in[0];
    const int*   ei       = (const int*)d_in[1];
    const float* Wl_stack = (const float*)d_in[2];
    const float* Wr_stack = (const float*)d_in[3];
    const float* b_stack  = (const float*)d_in[4];
    const float* Wl_out   = (const float*)d_in[5];
    const float* Wr_out   = (const float*)d_in[6];
    const float* b_out    = (const float*)d_in[7];
    float* out = (float*)d_out;

    unsigned short* hb = (unsigned short*)d_ws;        // [NNP,128]
    unsigned short* Yb = hb + (size_t)NNP * 128;       // [NNP,128]
    unsigned short* Zb = Yb + (size_t)NNP * 128;       // [NNP,128]
    unsigned short* WT = Zb + (size_t)NNP * 128;       // 114688 elems
    unsigned long long* ebuf = (unsigned long long*)(WT + 114688);  // [NE]
    int* row_off = (int*)(ebuf + NE);                  // [NN+1]
    int* csr     = row_off + NN + 1;                   // [NE]
    int* bcnt    = csr + NE;                           // [NBK]
    int* boff    = bcnt + NBK;                         // [NBK+1]
    int* bcur    = boff + NBK + 1;                     // [NBK]

    const int* src = ei;
    const int* dst = ei + NE;

    // bucketed CSR build
    (void)hipMemsetAsync(bcnt, 0, NBK * sizeof(int), stream);
    kb_hist<<<NSC, 256, 0, stream>>>(dst, bcnt);
    kb_scan<<<1, 512, 0, stream>>>(bcnt, boff, bcur);
    kb_scatter<<<NSC, 256, 0, stream>>>(src, dst, bcur, ebuf);
    kb_csr<<<NBK, 256, 0, stream>>>(ebuf, boff, row_off, csr);

    // weights -> bf16 transposed
    k_prep_wt<<<448, 256, 0, stream>>>(Wl_stack, Wr_stack, Wl_out, Wr_out, WT);

    // layer 0 (fp32 x read directly, converted in-register)
    k_mm<128, true><<<NNP / 128, 256, 0, stream>>>(x, WT, Yb, Zb);
    k_aggb<128, true><<<(NN + 3) / 4, 256, 0, stream>>>(Yb, Zb, row_off, csr,
                                                        b_stack, hb, nullptr);
    // layers 1..2
    for (int l = 1; l < 3; ++l) {
        k_mm<128, false><<<NNP / 128, 256, 0, stream>>>(hb, WT + l * 32768, Yb, Zb);
        k_aggb<128, true><<<(NN + 3) / 4, 256, 0, stream>>>(Yb, Zb, row_off, csr,
                                                            b_stack + l * 128, hb, nullptr);
    }
    // final layer
    k_mm<64, false><<<NNP / 128, 256, 0, stream>>>(hb, WT + 98304, Yb, Zb);
    k_aggb<64, false><<<(NN + 3) / 4, 256, 0, stream>>>(Yb, Zb, row_off, csr,
                                                        b_out, nullptr, out);
}